// Round 13
// baseline (2486.588 us; speedup 1.0000x reference)
//
#include <hip/hip_runtime.h>

#define T_LEN 16384
#define HDIM 64
#define BATCH 64
#define RING  128            // 2 chunks of 64 steps (16 KB f16 ring)

// K = DELAY / OS_FACTOR = 1/1.5 = 2/3
#define KBLEND      (2.0f / 3.0f)
#define ONE_MINUS_K (1.0f / 3.0f)
#define KK          (KBLEND * ONE_MINUS_K)

// tanh(x) = 1 - 2/(1 + exp2(C2*x)); C2 = 2*log2(e).
// We transport r = 1/(1+exp2(C2*arg)) and fold cell = 1-2r into the algebra:
//   W·cell = Wsum - 2·(W·r),  Wsum[l] = sum_k W_f16[l][k]
#define C2     2.8853900817779268f
#define C2K    (C2 * KBLEND)
#define C2KK   (C2 * KK)
#define N2C2K  (-2.0f * C2K)
#define N2C2KK (-2.0f * C2KK)

typedef _Float16 f16x8 __attribute__((ext_vector_type(8)));
typedef float    f32x4 __attribute__((ext_vector_type(4)));

__device__ __forceinline__ float lane_bcast(float v, int lane) {
    return __int_as_float(__builtin_amdgcn_readlane(__float_as_int(v), lane));
}

// waves_per_eu(1,1): 512-VGPR budget; producer and consumer waves land on
// different EUs so the producer keeps a SIMD's issue bandwidth to itself.
__global__ __launch_bounds__(2 * HDIM)
__attribute__((amdgpu_waves_per_eu(1, 1)))
void rnn_delayline_kernel(
    const float* __restrict__ x,      // [B, T, 1]
    const float* __restrict__ Wih,    // [H, 1]
    const float* __restrict__ Whh,    // [H, H] row-major
    const float* __restrict__ bih,    // [H]
    const float* __restrict__ bhh,    // [H]
    float* __restrict__ out_states,   // [B, T, H]
    float* __restrict__ out_hlast)    // [B, H]
{
    const int tid  = threadIdx.x;
    const int lane = tid & (HDIM - 1);
    const int b    = blockIdx.x;

    __shared__ __align__(16) _Float16 ring[RING][HDIM];   // r ring (16 KB)
    __shared__ int flag;                                   // chunks published

    if (tid == 0) flag = 0;
    __syncthreads();        // once, before the sequential work

    const float* xb = x + (size_t)b * T_LEN;
    const int NCHUNK = T_LEN / HDIM;   // 256

    if (tid < HDIM) {
        // ================= wave 0: the serial dependence chain =================
        // B fragments: W^T chunks for mfma_f32_16x16x32_f16 (round-10 proven).
        f16x8 Bf[8];   // [j*2 + s]
        {
            const int n = lane & 15, g = lane >> 4;
            #pragma unroll
            for (int j = 0; j < 4; ++j) {
                const float* wrow = Whh + (j * 16 + n) * HDIM;
                #pragma unroll
                for (int s = 0; s < 2; ++s) {
                    const float4* wp = reinterpret_cast<const float4*>(wrow + s * 32 + g * 8);
                    float4 v0 = wp[0], v1 = wp[1];
                    Bf[j*2+s] = (f16x8){(_Float16)v0.x, (_Float16)v0.y,
                                        (_Float16)v0.z, (_Float16)v0.w,
                                        (_Float16)v1.x, (_Float16)v1.y,
                                        (_Float16)v1.z, (_Float16)v1.w};
                }
            }
        }

        const float wihC2  = C2 * Wih[lane];
        const float biasC2 = C2 * (bih[lane] + bhh[lane]);

        // Row sum of the f16-rounded W row (must match MFMA arithmetic).
        float Wsum = 0.0f;
        #pragma unroll 16
        for (int k = 0; k < HDIM; ++k)
            Wsum += (float)(_Float16)Whh[lane * HDIM + k];

        const float cWsum   = C2KK * Wsum;           // G-update constant
        const float biasC2W = biasC2 + C2K * Wsum;   // bias + Wsum fold

        const int  g8    = (lane >> 4) * 8;
        const bool selLo = ((lane >> 4) & 1) != 0;
        const bool selHi = ((lane >> 4) & 2) != 0;

        // State: dotm = (W·r)_{t-1} raw; G = C2(1-K)d_{t-2}; cbW = next targ base.
        // dotm_init = Wsum/2 makes targ_0 = C2*xpre_0 exactly (d_{-1}=0).
        float G = 0.0f;
        float dotm = 0.5f * Wsum;
        float cbW  = fmaf(xb[0], wihC2, biasC2W);

        float xcur = xb[lane];

        for (int c = 0; c < NCHUNK; ++c) {
            float xnext = 0.0f;
            if (c + 1 < NCHUNK) xnext = xb[(size_t)(c + 1) * HDIM + lane];
            const int sbase = (c & 1) * 64;

            #pragma unroll 4
            for (int tt = 0; tt < HDIM; ++tt) {
                // Pin: weight frags are loop-carried asm outputs -> resident.
                asm volatile("" : "+v"(Bf[0]), "+v"(Bf[1]), "+v"(Bf[2]), "+v"(Bf[3]),
                                  "+v"(Bf[4]), "+v"(Bf[5]), "+v"(Bf[6]), "+v"(Bf[7]));

                // ---- critical chain: fma -> exp2 -> add -> rcp -> cvt -> write
                float targ = fmaf(N2C2K, dotm, cbW);       // C2 * arg_t
                float e    = __builtin_amdgcn_exp2f(targ);
                float rr   = __builtin_amdgcn_rcpf(1.0f + e);   // r = 1/(1+e)

                const int slot = sbase + tt;
                ring[slot][lane] = (_Float16)rr;           // publish (in-order DS)

                // A frags: 2x ds_read_b128, row-uniform per 16-lane group
                f16x8 a0 = *reinterpret_cast<const f16x8*>(&ring[slot][g8]);
                f16x8 a1 = *reinterpret_cast<const f16x8*>(&ring[slot][32 + g8]);
                __builtin_amdgcn_sched_barrier(0);   // window work stays below

                // ---- window: off-chain work inside the LDS round-trip ----
                G = fmaf(N2C2KK, dotm, fmaf(ONE_MINUS_K, G, cWsum));  // -> G_t
                float xsl = (tt == HDIM - 1) ? xnext : xcur;
                float xt1 = lane_bcast(xsl, (tt + 1) & (HDIM - 1));   // x_{t+1}
                cbW = fmaf(xt1, wihC2, biasC2W) + G;

                // ---- matvec: 8 INDEPENDENT MFMAs (flat DAG, C=0) ----
                const f32x4 z = (f32x4){0.0f, 0.0f, 0.0f, 0.0f};
                f32x4 d0a = __builtin_amdgcn_mfma_f32_16x16x32_f16(a0, Bf[0], z, 0, 0, 0);
                f32x4 d1a = __builtin_amdgcn_mfma_f32_16x16x32_f16(a0, Bf[2], z, 0, 0, 0);
                f32x4 d2a = __builtin_amdgcn_mfma_f32_16x16x32_f16(a0, Bf[4], z, 0, 0, 0);
                f32x4 d3a = __builtin_amdgcn_mfma_f32_16x16x32_f16(a0, Bf[6], z, 0, 0, 0);
                f32x4 d0b = __builtin_amdgcn_mfma_f32_16x16x32_f16(a1, Bf[1], z, 0, 0, 0);
                f32x4 d1b = __builtin_amdgcn_mfma_f32_16x16x32_f16(a1, Bf[3], z, 0, 0, 0);
                f32x4 d2b = __builtin_amdgcn_mfma_f32_16x16x32_f16(a1, Bf[5], z, 0, 0, 0);
                f32x4 d3b = __builtin_amdgcn_mfma_f32_16x16x32_f16(a1, Bf[7], z, 0, 0, 0);

                // ---- two parallel select trees + merge (W·r raw) ----
                float ta01 = selLo ? d1a[0] : d0a[0];
                float ta23 = selLo ? d3a[0] : d2a[0];
                float ta   = selHi ? ta23 : ta01;
                float tb01 = selLo ? d1b[0] : d0b[0];
                float tb23 = selLo ? d3b[0] : d2b[0];
                float tb   = selHi ? tb23 : tb01;
                dotm = ta + tb;                            // (W·r)_t
            }

            xcur = xnext;
            // publish chunk c (release: drains this wave's DS queue first)
            if (lane == 0)
                __hip_atomic_store(&flag, c + 1, __ATOMIC_RELEASE,
                                   __HIP_MEMORY_SCOPE_WORKGROUP);
        }
    } else {
        // ============ wave 1: h recurrence + all global stores ============
        float h = 0.0f;
        float* outp = out_states + (size_t)b * T_LEN * HDIM + lane;

        for (int c = 0; c < NCHUNK; ++c) {
            while (__hip_atomic_load(&flag, __ATOMIC_ACQUIRE,
                                     __HIP_MEMORY_SCOPE_WORKGROUP) <= c) {
                __builtin_amdgcn_s_sleep(2);
            }
            const int sbase = (c & 1) * 64;
            #pragma unroll 4
            for (int tt = 0; tt < HDIM; ++tt) {
                float rr   = (float)ring[sbase + tt][lane];
                float cell = fmaf(-2.0f, rr, 1.0f);   // cell = 1 - 2r (matches dot path)
                h = fmaf(KBLEND, cell - h, h);        // h_t = h + K*(cell-h)
                *outp = h;                            // coalesced 256B/wave store
                outp += HDIM;
            }
        }
        out_hlast[b * HDIM + lane] = h;
    }
}

extern "C" void kernel_launch(void* const* d_in, const int* in_sizes, int n_in,
                              void* d_out, int out_size, void* d_ws, size_t ws_size,
                              hipStream_t stream) {
    const float* x   = (const float*)d_in[0];
    const float* Wih = (const float*)d_in[1];
    const float* Whh = (const float*)d_in[2];
    const float* bih = (const float*)d_in[3];
    const float* bhh = (const float*)d_in[4];

    float* out_states = (float*)d_out;
    float* out_hlast  = out_states + (size_t)BATCH * T_LEN * HDIM;

    rnn_delayline_kernel<<<dim3(BATCH), dim3(2 * HDIM), 0, stream>>>(
        x, Wih, Whh, bih, bhh, out_states, out_hlast);
}

// Round 15
// 2377.583 us; speedup vs baseline: 1.0458x; 1.0458x over previous
//
#include <hip/hip_runtime.h>

#define T_LEN 16384
#define HDIM 64
#define BATCH 64
#define RING  128            // 2 chunks of 64 steps (16 KB f16 ring)

// K = DELAY / OS_FACTOR = 1/1.5 = 2/3
#define KBLEND      (2.0f / 3.0f)
#define ONE_MINUS_K (1.0f / 3.0f)

// tanh(x) = 1 - 2/(1 + exp2(C2*x)); C2 = 2*log2(e).
// B-frags are pre-scaled by C2K so MFMA(+C-injection) outputs targ directly:
//   targ_{t+1} = sum_k (C2K*W)[h][k]*cell_k + cb_{t+1}   (cb injected via C reg0)
#define C2    2.8853900817779268f
#define C2K   (C2 * KBLEND)

typedef _Float16 f16x8 __attribute__((ext_vector_type(8)));
typedef float    f32x4 __attribute__((ext_vector_type(4)));

__device__ __forceinline__ float lane_bcast(float v, int lane) {
    return __int_as_float(__builtin_amdgcn_readlane(__float_as_int(v), lane));
}

// waves_per_eu(1,1): 512-VGPR budget; producer and consumer waves land on
// different EUs so the producer keeps a SIMD's issue bandwidth to itself.
__global__ __launch_bounds__(2 * HDIM)
__attribute__((amdgpu_waves_per_eu(1, 1)))
void rnn_delayline_kernel(
    const float* __restrict__ x,      // [B, T, 1]
    const float* __restrict__ Wih,    // [H, 1]
    const float* __restrict__ Whh,    // [H, H] row-major
    const float* __restrict__ bih,    // [H]
    const float* __restrict__ bhh,    // [H]
    float* __restrict__ out_states,   // [B, T, H]
    float* __restrict__ out_hlast)    // [B, H]
{
    const int tid  = threadIdx.x;
    const int lane = tid & (HDIM - 1);
    const int b    = blockIdx.x;

    __shared__ __align__(16) _Float16 ring[RING][HDIM];   // cell ring (16 KB)
    __shared__ int flag;                                   // chunks published

    if (tid == 0) flag = 0;
    __syncthreads();        // once, before the sequential work

    const float* xb = x + (size_t)b * T_LEN;
    const int NCHUNK = T_LEN / HDIM;   // 256

    if (tid < HDIM) {
        // ================= wave 0: the serial dependence chain =================
        // B fragments: (C2K * W)^T chunks for mfma_f32_16x16x32_f16.
        f16x8 Bf[8];   // [j*2 + s]
        {
            const int n = lane & 15, g = lane >> 4;
            #pragma unroll
            for (int j = 0; j < 4; ++j) {
                const float* wrow = Whh + (j * 16 + n) * HDIM;
                #pragma unroll
                for (int s = 0; s < 2; ++s) {
                    const float4* wp = reinterpret_cast<const float4*>(wrow + s * 32 + g * 8);
                    float4 v0 = wp[0], v1 = wp[1];
                    Bf[j*2+s] = (f16x8){(_Float16)(C2K * v0.x), (_Float16)(C2K * v0.y),
                                        (_Float16)(C2K * v0.z), (_Float16)(C2K * v0.w),
                                        (_Float16)(C2K * v1.x), (_Float16)(C2K * v1.y),
                                        (_Float16)(C2K * v1.z), (_Float16)(C2K * v1.w)};
                }
            }
        }

        const float wihC2  = C2 * Wih[lane];
        const float biasC2 = C2 * (bih[lane] + bhh[lane]);

        const int  g8    = (lane >> 4) * 8;
        const bool selLo = ((lane >> 4) & 1) != 0;
        const bool selHi = ((lane >> 4) & 2) != 0;

        // State: targ_t arrives from the previous MFMA's select (C-injected).
        // G_{t+1} = (1-K)*(G_t + targ_t - cb_t);  cb_{t+1} = C2*xpre_{t+1} + G_{t+1}.
        float G = 0.0f;
        float cbPrev = fmaf(xb[0], wihC2, biasC2);   // cb_0
        float targ   = cbPrev;                        // targ_0 (dot_{-1} = 0)

        float xcur = xb[lane];

        for (int c = 0; c < NCHUNK; ++c) {
            float xnext = 0.0f;
            if (c + 1 < NCHUNK) xnext = xb[(size_t)(c + 1) * HDIM + lane];
            const int sbase = (c & 1) * 64;

            #pragma unroll 4
            for (int tt = 0; tt < HDIM; ++tt) {
                // Pin: weight frags are loop-carried asm outputs -> resident.
                asm volatile("" : "+v"(Bf[0]), "+v"(Bf[1]), "+v"(Bf[2]), "+v"(Bf[3]),
                                  "+v"(Bf[4]), "+v"(Bf[5]), "+v"(Bf[6]), "+v"(Bf[7]));

                // ---- critical chain: exp2 -> add -> rcp -> fma -> cvt -> write
                float e    = __builtin_amdgcn_exp2f(targ);
                float r    = __builtin_amdgcn_rcpf(1.0f + e);
                float cell = fmaf(-2.0f, r, 1.0f);        // tanh(arg)

                const int slot = sbase + tt;
                ring[slot][lane] = (_Float16)cell;        // publish (in-order DS)

                // A frags: 2x ds_read_b128, row-uniform per 16-lane group
                f16x8 a0 = *reinterpret_cast<const f16x8*>(&ring[slot][g8]);
                f16x8 a1 = *reinterpret_cast<const f16x8*>(&ring[slot][32 + g8]);

                // ---- window: off-chain work inside the LDS round-trip ----
                G = ONE_MINUS_K * (G + (targ - cbPrev));  // -> G_{t+1}
                float xsl = (tt == HDIM - 1) ? xnext : xcur;
                float xt1 = lane_bcast(xsl, (tt + 1) & (HDIM - 1));  // x_{t+1}
                float cb  = fmaf(xt1, wihC2, biasC2) + G; // cb_{t+1}
                cbPrev = cb;
                const f32x4 cin = (f32x4){cb, 0.0f, 0.0f, 0.0f};

                // ---- matvec + C-injection: 8 MFMA, 2-chained per tile ----
                f32x4 d0 = __builtin_amdgcn_mfma_f32_16x16x32_f16(a0, Bf[0], cin, 0, 0, 0);
                f32x4 d1 = __builtin_amdgcn_mfma_f32_16x16x32_f16(a0, Bf[2], cin, 0, 0, 0);
                f32x4 d2 = __builtin_amdgcn_mfma_f32_16x16x32_f16(a0, Bf[4], cin, 0, 0, 0);
                f32x4 d3 = __builtin_amdgcn_mfma_f32_16x16x32_f16(a0, Bf[6], cin, 0, 0, 0);
                d0 = __builtin_amdgcn_mfma_f32_16x16x32_f16(a1, Bf[1], d0, 0, 0, 0);
                d1 = __builtin_amdgcn_mfma_f32_16x16x32_f16(a1, Bf[3], d1, 0, 0, 0);
                d2 = __builtin_amdgcn_mfma_f32_16x16x32_f16(a1, Bf[5], d2, 0, 0, 0);
                d3 = __builtin_amdgcn_mfma_f32_16x16x32_f16(a1, Bf[7], d3, 0, 0, 0);

                // ---- select targ_{t+1}: tile lane>>4, col lane&15, reg 0 ----
                float t01 = selLo ? d1[0] : d0[0];
                float t23 = selLo ? d3[0] : d2[0];
                targ = selHi ? t23 : t01;
            }

            xcur = xnext;
            // publish chunk c (release: drains this wave's DS queue first)
            if (lane == 0)
                __hip_atomic_store(&flag, c + 1, __ATOMIC_RELEASE,
                                   __HIP_MEMORY_SCOPE_WORKGROUP);
        }
    } else {
        // ============ wave 1: h recurrence + all global stores ============
        float h = 0.0f;
        float* outp = out_states + (size_t)b * T_LEN * HDIM + lane;

        for (int c = 0; c < NCHUNK; ++c) {
            while (__hip_atomic_load(&flag, __ATOMIC_ACQUIRE,
                                     __HIP_MEMORY_SCOPE_WORKGROUP) <= c) {
                __builtin_amdgcn_s_sleep(2);
            }
            const int sbase = (c & 1) * 64;
            #pragma unroll 4
            for (int tt = 0; tt < HDIM; ++tt) {
                float cell = (float)ring[sbase + tt][lane];
                h = fmaf(KBLEND, cell - h, h);      // h_t = h + K*(cell-h)
                *outp = h;                          // coalesced 256B/wave store
                outp += HDIM;
            }
        }
        out_hlast[b * HDIM + lane] = h;
    }
}

extern "C" void kernel_launch(void* const* d_in, const int* in_sizes, int n_in,
                              void* d_out, int out_size, void* d_ws, size_t ws_size,
                              hipStream_t stream) {
    const float* x   = (const float*)d_in[0];
    const float* Wih = (const float*)d_in[1];
    const float* Whh = (const float*)d_in[2];
    const float* bih = (const float*)d_in[3];
    const float* bhh = (const float*)d_in[4];

    float* out_states = (float*)d_out;
    float* out_hlast  = out_states + (size_t)BATCH * T_LEN * HDIM;

    rnn_delayline_kernel<<<dim3(BATCH), dim3(2 * HDIM), 0, stream>>>(
        x, Wih, Whh, bih, bhh, out_states, out_hlast);
}

// Round 16
// 2330.936 us; speedup vs baseline: 1.0668x; 1.0200x over previous
//
#include <hip/hip_runtime.h>

#define T_LEN 16384
#define HDIM 64
#define BATCH 64
#define RING  128            // 2 chunks of 64 steps (16 KB f16 ring)

// K = DELAY / OS_FACTOR = 1/1.5 = 2/3
#define KBLEND      (2.0f / 3.0f)
#define ONE_MINUS_K (1.0f / 3.0f)
#define KK          (KBLEND * ONE_MINUS_K)

// tanh(x) = 1 - 2/(1 + exp2(C2*x)); C2 = 2*log2(e). Exact algebra.
#define C2    2.8853900817779268f
#define C2K   (C2 * KBLEND)
#define C2KK  (C2 * KK)

typedef _Float16 f16x8 __attribute__((ext_vector_type(8)));
typedef float    f32x4 __attribute__((ext_vector_type(4)));

__device__ __forceinline__ float lane_bcast(float v, int lane) {
    return __int_as_float(__builtin_amdgcn_readlane(__float_as_int(v), lane));
}

// waves_per_eu(1,1): 512-VGPR budget; the 2 waves land on different EUs, so
// the producer keeps a whole SIMD's issue bandwidth to itself.
__global__ __launch_bounds__(2 * HDIM)
__attribute__((amdgpu_waves_per_eu(1, 1)))
void rnn_delayline_kernel(
    const float* __restrict__ x,      // [B, T, 1]
    const float* __restrict__ Wih,    // [H, 1]
    const float* __restrict__ Whh,    // [H, H] row-major
    const float* __restrict__ bih,    // [H]
    const float* __restrict__ bhh,    // [H]
    float* __restrict__ out_states,   // [B, T, H]
    float* __restrict__ out_hlast)    // [B, H]
{
    const int tid  = threadIdx.x;
    const int lane = tid & (HDIM - 1);
    const int b    = blockIdx.x;

    __shared__ __align__(16) _Float16 ring[RING][HDIM];   // cell ring (16 KB)
    __shared__ int flag;                                   // chunks published

    if (tid == 0) flag = 0;
    __syncthreads();        // once, before the sequential work

    const float* xb = x + (size_t)b * T_LEN;
    const int NCHUNK = T_LEN / HDIM;   // 256

    if (tid < HDIM) {
        // ================= wave 0: the serial dependence chain =================
        // B fragments: W^T chunks for mfma_f32_16x16x32_f16 (round-10 proven).
        f16x8 Bf[8];   // [j*2 + s]
        {
            const int n = lane & 15, g = lane >> 4;
            #pragma unroll
            for (int j = 0; j < 4; ++j) {
                const float* wrow = Whh + (j * 16 + n) * HDIM;
                #pragma unroll
                for (int s = 0; s < 2; ++s) {
                    const float4* wp = reinterpret_cast<const float4*>(wrow + s * 32 + g * 8);
                    float4 v0 = wp[0], v1 = wp[1];
                    Bf[j*2+s] = (f16x8){(_Float16)v0.x, (_Float16)v0.y,
                                        (_Float16)v0.z, (_Float16)v0.w,
                                        (_Float16)v1.x, (_Float16)v1.y,
                                        (_Float16)v1.z, (_Float16)v1.w};
                }
            }
        }

        const float wihC2  = C2 * Wih[lane];
        const float biasC2 = C2 * (bih[lane] + bhh[lane]);

        const int  g8    = (lane >> 4) * 8;
        const bool selLo = ((lane >> 4) & 1) != 0;
        const bool selHi = ((lane >> 4) & 2) != 0;

        float dot = 0.0f, G = 0.0f;
        float xcur = xb[lane];

        for (int c = 0; c < NCHUNK; ++c) {
            float xnext = 0.0f;
            if (c + 1 < NCHUNK) xnext = xb[(size_t)(c + 1) * HDIM + lane];
            const int sbase = (c & 1) * 64;

            #pragma unroll 4
            for (int tt = 0; tt < HDIM; ++tt) {
                // Pin: weight frags are loop-carried asm outputs -> resident.
                asm volatile("" : "+v"(Bf[0]), "+v"(Bf[1]), "+v"(Bf[2]), "+v"(Bf[3]),
                                  "+v"(Bf[4]), "+v"(Bf[5]), "+v"(Bf[6]), "+v"(Bf[7]));

                // off-chain inputs
                float xt = lane_bcast(xcur, tt);
                float cb = fmaf(xt, wihC2, biasC2) + G;

                // critical chain: fma -> exp2 -> add -> rcp -> fma
                float targ = fmaf(C2K, dot, cb);
                float e    = __builtin_amdgcn_exp2f(targ);
                float r    = __builtin_amdgcn_rcpf(1.0f + e);
                float cell = fmaf(-2.0f, r, 1.0f);        // tanh(arg)

                const int slot = sbase + tt;
                ring[slot][lane] = (_Float16)cell;        // publish (in-order DS)

                G = fmaf(ONE_MINUS_K, G, C2KK * dot);     // off-chain

                // A frags: 2x ds_read_b128, row-uniform per 16-lane group
                f16x8 a0 = *reinterpret_cast<const f16x8*>(&ring[slot][g8]);
                f16x8 a1 = *reinterpret_cast<const f16x8*>(&ring[slot][32 + g8]);

                // matvec via 8 MFMA (4 n-tiles x 2 k-tiles, f32 accum)
                f32x4 d0 = __builtin_amdgcn_mfma_f32_16x16x32_f16(a0, Bf[0], (f32x4){0,0,0,0}, 0, 0, 0);
                f32x4 d1 = __builtin_amdgcn_mfma_f32_16x16x32_f16(a0, Bf[2], (f32x4){0,0,0,0}, 0, 0, 0);
                f32x4 d2 = __builtin_amdgcn_mfma_f32_16x16x32_f16(a0, Bf[4], (f32x4){0,0,0,0}, 0, 0, 0);
                f32x4 d3 = __builtin_amdgcn_mfma_f32_16x16x32_f16(a0, Bf[6], (f32x4){0,0,0,0}, 0, 0, 0);
                d0 = __builtin_amdgcn_mfma_f32_16x16x32_f16(a1, Bf[1], d0, 0, 0, 0);
                d1 = __builtin_amdgcn_mfma_f32_16x16x32_f16(a1, Bf[3], d1, 0, 0, 0);
                d2 = __builtin_amdgcn_mfma_f32_16x16x32_f16(a1, Bf[5], d2, 0, 0, 0);
                d3 = __builtin_amdgcn_mfma_f32_16x16x32_f16(a1, Bf[7], d3, 0, 0, 0);

                // select dot[lane]: D_{lane>>4}, col lane&15, reg 0
                float t01 = selLo ? d1[0] : d0[0];
                float t23 = selLo ? d3[0] : d2[0];
                dot = selHi ? t23 : t01;
            }

            xcur = xnext;
            // publish chunk c (release: drains this wave's DS queue first)
            if (lane == 0)
                __hip_atomic_store(&flag, c + 1, __ATOMIC_RELEASE,
                                   __HIP_MEMORY_SCOPE_WORKGROUP);
        }
    } else {
        // ================= wave 1: h recurrence + all global stores =================
        float h = 0.0f;
        float* outp = out_states + (size_t)b * T_LEN * HDIM + lane;

        for (int c = 0; c < NCHUNK; ++c) {
            // acquire-poll; s_sleep keeps the DS pipe clear for wave 0
            while (__hip_atomic_load(&flag, __ATOMIC_ACQUIRE,
                                     __HIP_MEMORY_SCOPE_WORKGROUP) <= c) {
                __builtin_amdgcn_s_sleep(2);
            }
            const int sbase = (c & 1) * 64;
            #pragma unroll 4
            for (int tt = 0; tt < HDIM; ++tt) {
                float cell = (float)ring[sbase + tt][lane];
                h = fmaf(KBLEND, cell - h, h);      // h_t = h + K*(cell-h)
                *outp = h;                          // coalesced 256B/wave store
                outp += HDIM;
            }
        }
        out_hlast[b * HDIM + lane] = h;
    }
}

extern "C" void kernel_launch(void* const* d_in, const int* in_sizes, int n_in,
                              void* d_out, int out_size, void* d_ws, size_t ws_size,
                              hipStream_t stream) {
    const float* x   = (const float*)d_in[0];
    const float* Wih = (const float*)d_in[1];
    const float* Whh = (const float*)d_in[2];
    const float* bih = (const float*)d_in[3];
    const float* bhh = (const float*)d_in[4];

    float* out_states = (float*)d_out;
    float* out_hlast  = out_states + (size_t)BATCH * T_LEN * HDIM;

    rnn_delayline_kernel<<<dim3(BATCH), dim3(2 * HDIM), 0, stream>>>(
        x, Wih, Whh, bih, bhh, out_states, out_hlast);
}